// Round 1
// baseline (671.581 us; speedup 1.0000x reference)
//
#include <hip/hip_runtime.h>
#include <math.h>

#define NN 2048
#define BB 4
#define HD 128
#define CNUM 8

// K1: per-center squared distances, mean distance, top-3 NN, incidence values,
// edge degrees, atomic vertex degrees.
__global__ void k_dist_topk(const float* __restrict__ x,
                            int* __restrict__ idx, float* __restrict__ vals,
                            float* __restrict__ de, float* __restrict__ dv) {
    __shared__ float xs[NN], ys[NN], zs[NN], sn[NN];
    const int b = blockIdx.y;
    const float* xb = x + (size_t)b * NN * 3;
    for (int t = threadIdx.x; t < NN; t += blockDim.x) {
        float a = xb[3 * t], c = xb[3 * t + 1], d = xb[3 * t + 2];
        xs[t] = a; ys[t] = c; zs[t] = d;
        sn[t] = a * a + c * c + d * d;
    }
    __syncthreads();
    const int i = blockIdx.x * blockDim.x + threadIdx.x;
    const float xi = xs[i], yi = ys[i], zi = zs[i], sqi = sn[i];
    float s0 = INFINITY, s1 = INFINITY, s2 = INFINITY;
    int i0 = 0, i1 = 0, i2 = 0;
    float dsum = 0.f;
    for (int j = 0; j < NN; ++j) {
        float dot = xi * xs[j] + yi * ys[j] + zi * zs[j];
        float sq = sqi + sn[j] - 2.0f * dot;
        sq = fmaxf(sq, 0.0f);
        dsum += sqrtf(sq + 1e-12f);
        if (sq < s2) {                     // strict <: stable tie-break like XLA top_k
            if (sq < s1) {
                s2 = s1; i2 = i1;
                if (sq < s0) { s1 = s0; i1 = i0; s0 = sq; i0 = j; }
                else         { s1 = sq; i1 = j; }
            } else { s2 = sq; i2 = j; }
        }
    }
    const float avg = dsum * (1.0f / NN);
    const float inva2 = 1.0f / (avg * avg);
    const float v0 = expf(-s0 * inva2);
    const float v1 = expf(-s1 * inva2);
    const float v2 = expf(-s2 * inva2);
    const int base = (b * NN + i) * 3;
    idx[base] = i0; idx[base + 1] = i1; idx[base + 2] = i2;
    vals[base] = v0; vals[base + 1] = v1; vals[base + 2] = v2;
    de[b * NN + i] = v0 + v1 + v2;
    atomicAdd(&dv[b * NN + i0], v0);
    atomicAdd(&dv[b * NN + i1], v1);
    atomicAdd(&dv[b * NN + i2], v2);
}

// K2: first G-application on W1. One block per edge; gather 3 rows, scatter 3 rows.
__global__ void k_conv1(const float* __restrict__ W1, const int* __restrict__ idx,
                        const float* __restrict__ vals, const float* __restrict__ de,
                        const float* __restrict__ dv, float* __restrict__ Z1) {
    const int e = blockIdx.x, b = blockIdx.y, h = threadIdx.x;
    const int base = (b * NN + e) * 3;
    const int j0 = idx[base], j1 = idx[base + 1], j2 = idx[base + 2];
    const float v0 = vals[base], v1 = vals[base + 1], v2 = vals[base + 2];
    const float ide = 1.0f / de[b * NN + e];
    const float g0 = v0 * rsqrtf(dv[b * NN + j0]);
    const float g1 = v1 * rsqrtf(dv[b * NN + j1]);
    const float g2 = v2 * rsqrtf(dv[b * NN + j2]);
    const float y = ide * (g0 * W1[j0 * HD + h] + g1 * W1[j1 * HD + h] + g2 * W1[j2 * HD + h]);
    atomicAdd(&Z1[((size_t)(b * NN + j0)) * HD + h], v0 * y);
    atomicAdd(&Z1[((size_t)(b * NN + j1)) * HD + h], v1 * y);
    atomicAdd(&Z1[((size_t)(b * NN + j2)) * HD + h], v2 * y);
}

// K3: second G-application on f1 = dv2*Z1 + b1.
__global__ void k_conv2(const float* __restrict__ b1, const int* __restrict__ idx,
                        const float* __restrict__ vals, const float* __restrict__ de,
                        const float* __restrict__ dv, const float* __restrict__ Z1,
                        float* __restrict__ Z2) {
    const int e = blockIdx.x, b = blockIdx.y, h = threadIdx.x;
    const int base = (b * NN + e) * 3;
    const int j0 = idx[base], j1 = idx[base + 1], j2 = idx[base + 2];
    const float v0 = vals[base], v1 = vals[base + 1], v2 = vals[base + 2];
    const float ide = 1.0f / de[b * NN + e];
    const float bh = b1[h];
    const float d0 = rsqrtf(dv[b * NN + j0]);
    const float d1 = rsqrtf(dv[b * NN + j1]);
    const float d2 = rsqrtf(dv[b * NN + j2]);
    const float f0 = d0 * Z1[((size_t)(b * NN + j0)) * HD + h] + bh;
    const float f1 = d1 * Z1[((size_t)(b * NN + j1)) * HD + h] + bh;
    const float f2 = d2 * Z1[((size_t)(b * NN + j2)) * HD + h] + bh;
    const float y = ide * (v0 * d0 * f0 + v1 * d1 * f1 + v2 * d2 * f2);
    atomicAdd(&Z2[((size_t)(b * NN + j0)) * HD + h], v0 * y);
    atomicAdd(&Z2[((size_t)(b * NN + j1)) * HD + h], v1 * y);
    atomicAdd(&Z2[((size_t)(b * NN + j2)) * HD + h], v2 * y);
}

// K4: f = dv2*Z2, max over nodes, classifier.
__global__ void k_pool(const float* __restrict__ Wc, const float* __restrict__ bc,
                       const float* __restrict__ dv, const float* __restrict__ Z2,
                       float* __restrict__ out) {
    __shared__ float sdv2[NN];
    __shared__ float smax[HD];
    const int b = blockIdx.x, h = threadIdx.x;
    for (int v = h; v < NN; v += blockDim.x) sdv2[v] = rsqrtf(dv[b * NN + v]);
    __syncthreads();
    float mx = -INFINITY;
    for (int v = 0; v < NN; ++v)
        mx = fmaxf(mx, sdv2[v] * Z2[((size_t)(b * NN + v)) * HD + h]);
    smax[h] = mx;
    __syncthreads();
    if (h < CNUM) {
        float acc = bc[h];
        for (int q = 0; q < HD; ++q) acc += smax[q] * Wc[q * CNUM + h];
        out[b * CNUM + h] = acc;
    }
}

extern "C" void kernel_launch(void* const* d_in, const int* in_sizes, int n_in,
                              void* d_out, int out_size, void* d_ws, size_t ws_size,
                              hipStream_t stream) {
    const float* x  = (const float*)d_in[0];   // [B,N,3]
    const float* W1 = (const float*)d_in[1];   // [N,H1]
    const float* b1 = (const float*)d_in[2];   // [H1]
    const float* Wc = (const float*)d_in[3];   // [H1,C]
    const float* bc = (const float*)d_in[4];   // [C]
    float* out = (float*)d_out;                // [B,C]

    float* ws = (float*)d_ws;
    float* dv   = ws;                                  // B*N           (zeroed)
    float* Z1   = dv + BB * NN;                        // B*N*HD        (zeroed)
    float* Z2   = Z1 + (size_t)BB * NN * HD;           // B*N*HD        (zeroed)
    float* vals = Z2 + (size_t)BB * NN * HD;           // B*N*3
    float* de   = vals + BB * NN * 3;                  // B*N
    int*   idx  = (int*)(de + BB * NN);                // B*N*3

    // zero the contiguous [dv | Z1 | Z2] region
    hipMemsetAsync(dv, 0, (size_t)(BB * NN) * (1 + 2 * HD) * sizeof(float), stream);

    k_dist_topk<<<dim3(NN / 256, BB), 256, 0, stream>>>(x, idx, vals, de, dv);
    k_conv1<<<dim3(NN, BB), HD, 0, stream>>>(W1, idx, vals, de, dv, Z1);
    k_conv2<<<dim3(NN, BB), HD, 0, stream>>>(b1, idx, vals, de, dv, Z1, Z2);
    k_pool<<<BB, HD, 0, stream>>>(Wc, bc, dv, Z2, out);
}

// Round 2
// 188.054 us; speedup vs baseline: 3.5712x; 3.5712x over previous
//
#include <hip/hip_runtime.h>
#include <math.h>

#define NN 2048
#define BB 4
#define HD 128
#define CNUM 8
#define NPART 4
#define CPB 64              // centers per block in k_dist_topk
#define JS (NN / NPART)     // j-range per partial scan (512)
#define PCHUNK 64           // nodes per block in k_pool1
#define NCHUNKS (NN / PCHUNK)

// K1: per-center squared distances, mean distance, top-3 NN, incidence values,
// edge degrees, atomic vertex degrees. 4 threads cooperate per center, each
// scanning a 512-wide j range; partial top-3s merged through LDS.
__global__ __launch_bounds__(256) void k_dist_topk(
        const float* __restrict__ x,
        int* __restrict__ idx, float* __restrict__ vals,
        float* __restrict__ de, float* __restrict__ dv) {
    __shared__ float4 s4[NN];                 // (x,y,z,|p|^2) per node: 32 KB
    __shared__ float psq[NPART][CPB][3];
    __shared__ int   pix[NPART][CPB][3];
    __shared__ float pdsum[NPART][CPB];
    const int b = blockIdx.y;
    const float* xb = x + (size_t)b * NN * 3;
    for (int t = threadIdx.x; t < NN; t += 256) {
        float a = xb[3 * t], c = xb[3 * t + 1], d = xb[3 * t + 2];
        s4[t] = make_float4(a, c, d, a * a + c * c + d * d);
    }
    __syncthreads();
    const int lc = threadIdx.x & (CPB - 1);   // local center
    const int part = threadIdx.x >> 6;        // j-range id; whole wave shares part
    const int i = blockIdx.x * CPB + lc;
    const float4 ci = s4[i];
    float s0 = INFINITY, s1 = INFINITY, s2 = INFINITY;
    int i0 = -1, i1 = -1, i2 = -1;
    float dsum = 0.f;
    const int jbeg = part * JS;
    for (int j = jbeg; j < jbeg + JS; ++j) {
        float4 p = s4[j];                     // wave-uniform addr -> LDS broadcast
        float sq = fmaxf(ci.w + p.w - 2.0f * (ci.x * p.x + ci.y * p.y + ci.z * p.z), 0.0f);
        dsum += sqrtf(sq + 1e-12f);
        if (sq < s2) {                        // strict <: lower j wins ties
            if (sq < s1) {
                s2 = s1; i2 = i1;
                if (sq < s0) { s1 = s0; i1 = i0; s0 = sq; i0 = j; }
                else         { s1 = sq; i1 = j; }
            } else { s2 = sq; i2 = j; }
        }
    }
    psq[part][lc][0] = s0; psq[part][lc][1] = s1; psq[part][lc][2] = s2;
    pix[part][lc][0] = i0; pix[part][lc][1] = i1; pix[part][lc][2] = i2;
    pdsum[part][lc] = dsum;
    __syncthreads();
    if (part == 0) {
        float ds = dsum;
        for (int p = 1; p < NPART; ++p) {     // parts in increasing-j order
            ds += pdsum[p][lc];
            for (int k = 0; k < 3; ++k) {
                float sq = psq[p][lc][k]; int jj = pix[p][lc][k];
                if (sq < s2) {
                    if (sq < s1) {
                        s2 = s1; i2 = i1;
                        if (sq < s0) { s1 = s0; i1 = i0; s0 = sq; i0 = jj; }
                        else         { s1 = sq; i1 = jj; }
                    } else { s2 = sq; i2 = jj; }
                }
            }
        }
        const float avg = ds * (1.0f / NN);
        const float inva2 = 1.0f / (avg * avg);
        const float v0 = expf(-s0 * inva2);
        const float v1 = expf(-s1 * inva2);
        const float v2 = expf(-s2 * inva2);
        const int base = (b * NN + i) * 3;
        idx[base] = i0; idx[base + 1] = i1; idx[base + 2] = i2;
        vals[base] = v0; vals[base + 1] = v1; vals[base + 2] = v2;
        de[b * NN + i] = v0 + v1 + v2;
        atomicAdd(&dv[b * NN + i0], v0);
        atomicAdd(&dv[b * NN + i1], v1);
        atomicAdd(&dv[b * NN + i2], v2);
    }
}

// K2: first G-application on W1. One block per edge; gather 3 rows, scatter 3 rows.
__global__ void k_conv1(const float* __restrict__ W1, const int* __restrict__ idx,
                        const float* __restrict__ vals, const float* __restrict__ de,
                        const float* __restrict__ dv, float* __restrict__ Z1) {
    const int e = blockIdx.x, b = blockIdx.y, h = threadIdx.x;
    const int base = (b * NN + e) * 3;
    const int j0 = idx[base], j1 = idx[base + 1], j2 = idx[base + 2];
    const float v0 = vals[base], v1 = vals[base + 1], v2 = vals[base + 2];
    const float ide = 1.0f / de[b * NN + e];
    const float g0 = v0 * rsqrtf(dv[b * NN + j0]);
    const float g1 = v1 * rsqrtf(dv[b * NN + j1]);
    const float g2 = v2 * rsqrtf(dv[b * NN + j2]);
    const float y = ide * (g0 * W1[j0 * HD + h] + g1 * W1[j1 * HD + h] + g2 * W1[j2 * HD + h]);
    atomicAdd(&Z1[((size_t)(b * NN + j0)) * HD + h], v0 * y);
    atomicAdd(&Z1[((size_t)(b * NN + j1)) * HD + h], v1 * y);
    atomicAdd(&Z1[((size_t)(b * NN + j2)) * HD + h], v2 * y);
}

// K3: second G-application on f1 = dv2*Z1 + b1.
__global__ void k_conv2(const float* __restrict__ b1, const int* __restrict__ idx,
                        const float* __restrict__ vals, const float* __restrict__ de,
                        const float* __restrict__ dv, const float* __restrict__ Z1,
                        float* __restrict__ Z2) {
    const int e = blockIdx.x, b = blockIdx.y, h = threadIdx.x;
    const int base = (b * NN + e) * 3;
    const int j0 = idx[base], j1 = idx[base + 1], j2 = idx[base + 2];
    const float v0 = vals[base], v1 = vals[base + 1], v2 = vals[base + 2];
    const float ide = 1.0f / de[b * NN + e];
    const float bh = b1[h];
    const float d0 = rsqrtf(dv[b * NN + j0]);
    const float d1 = rsqrtf(dv[b * NN + j1]);
    const float d2 = rsqrtf(dv[b * NN + j2]);
    const float f0 = d0 * Z1[((size_t)(b * NN + j0)) * HD + h] + bh;
    const float f1 = d1 * Z1[((size_t)(b * NN + j1)) * HD + h] + bh;
    const float f2 = d2 * Z1[((size_t)(b * NN + j2)) * HD + h] + bh;
    const float y = ide * (v0 * d0 * f0 + v1 * d1 * f1 + v2 * d2 * f2);
    atomicAdd(&Z2[((size_t)(b * NN + j0)) * HD + h], v0 * y);
    atomicAdd(&Z2[((size_t)(b * NN + j1)) * HD + h], v1 * y);
    atomicAdd(&Z2[((size_t)(b * NN + j2)) * HD + h], v2 * y);
}

// K4a: partial max over 64-node chunks. grid (B, 32) x 128 threads.
__global__ void k_pool1(const float* __restrict__ dv, const float* __restrict__ Z2,
                        float* __restrict__ pmax) {
    const int b = blockIdx.x, ch = blockIdx.y, h = threadIdx.x;
    const int v0 = ch * PCHUNK;
    float mx = -INFINITY;
    for (int v = v0; v < v0 + PCHUNK; ++v) {
        const float d2 = rsqrtf(dv[b * NN + v]);          // uniform -> scalar/broadcast
        mx = fmaxf(mx, d2 * Z2[((size_t)(b * NN + v)) * HD + h]);
    }
    pmax[(b * NCHUNKS + ch) * HD + h] = mx;
}

// K4b: merge partial maxes + classifier. grid B x 128 threads.
__global__ void k_pool2(const float* __restrict__ Wc, const float* __restrict__ bc,
                        const float* __restrict__ pmax, float* __restrict__ out) {
    __shared__ float smax[HD];
    const int b = blockIdx.x, h = threadIdx.x;
    float mx = -INFINITY;
    for (int c = 0; c < NCHUNKS; ++c)
        mx = fmaxf(mx, pmax[(b * NCHUNKS + c) * HD + h]);
    smax[h] = mx;
    __syncthreads();
    if (h < CNUM) {
        float acc = bc[h];
        for (int q = 0; q < HD; ++q) acc += smax[q] * Wc[q * CNUM + h];
        out[b * CNUM + h] = acc;
    }
}

extern "C" void kernel_launch(void* const* d_in, const int* in_sizes, int n_in,
                              void* d_out, int out_size, void* d_ws, size_t ws_size,
                              hipStream_t stream) {
    const float* x  = (const float*)d_in[0];   // [B,N,3]
    const float* W1 = (const float*)d_in[1];   // [N,H1]
    const float* b1 = (const float*)d_in[2];   // [H1]
    const float* Wc = (const float*)d_in[3];   // [H1,C]
    const float* bc = (const float*)d_in[4];   // [C]
    float* out = (float*)d_out;                // [B,C]

    float* ws = (float*)d_ws;
    float* dv   = ws;                                  // B*N           (zeroed)
    float* Z1   = dv + BB * NN;                        // B*N*HD        (zeroed)
    float* Z2   = Z1 + (size_t)BB * NN * HD;           // B*N*HD        (zeroed)
    float* vals = Z2 + (size_t)BB * NN * HD;           // B*N*3
    float* de   = vals + BB * NN * 3;                  // B*N
    int*   idx  = (int*)(de + BB * NN);                // B*N*3
    float* pmax = (float*)(idx + BB * NN * 3);         // B*32*HD

    // zero the contiguous [dv | Z1 | Z2] region
    hipMemsetAsync(dv, 0, (size_t)(BB * NN) * (1 + 2 * HD) * sizeof(float), stream);

    k_dist_topk<<<dim3(NN / CPB, BB), 256, 0, stream>>>(x, idx, vals, de, dv);
    k_conv1<<<dim3(NN, BB), HD, 0, stream>>>(W1, idx, vals, de, dv, Z1);
    k_conv2<<<dim3(NN, BB), HD, 0, stream>>>(b1, idx, vals, de, dv, Z1, Z2);
    k_pool1<<<dim3(BB, NCHUNKS), HD, 0, stream>>>(dv, Z2, pmax);
    k_pool2<<<BB, HD, 0, stream>>>(Wc, bc, pmax, out);
}

// Round 3
// 185.264 us; speedup vs baseline: 3.6250x; 1.0151x over previous
//
#include <hip/hip_runtime.h>
#include <math.h>

#define NN 2048
#define BB 4
#define HD 128
#define CNUM 8
#define CPB 64              // centers per block (stage A)
#define NJB 4               // j-blocks (grid.y, stage A)
#define WPB 4               // waves per block = parts per j-block
#define JCH (NN / NJB)      // 512 nodes staged per block
#define JS (JCH / WPB)      // 128 j's per wave-part
#define PCHUNK 64           // nodes per block in k_pool1
#define NCHUNKS (NN / PCHUNK)

__device__ __forceinline__ void top3_insert(float sq, int j,
        float& s0, float& s1, float& s2, int& i0, int& i1, int& i2) {
    if (sq < s2) {                        // strict <: lower j wins ties
        if (sq < s1) {
            s2 = s1; i2 = i1;
            if (sq < s0) { s1 = s0; i1 = i0; s0 = sq; i0 = j; }
            else         { s1 = sq; i1 = j; }
        } else { s2 = sq; i2 = j; }
    }
}

// Stage A: partial top-3 + partial dsum per (b, center, j-block).
// grid (NN/CPB, NJB, BB) x 256 threads. Wave-uniform part -> LDS broadcast.
__global__ __launch_bounds__(256) void k_dist_part(
        const float* __restrict__ x,
        float* __restrict__ psq, int* __restrict__ pix, float* __restrict__ pds) {
    __shared__ float4 s4[JCH];            // 8 KB: this block's j-chunk
    __shared__ float msq[WPB][CPB][3];
    __shared__ int   mix[WPB][CPB][3];
    __shared__ float mds[WPB][CPB];
    const int b = blockIdx.z, jb = blockIdx.y;
    const float* xb = x + (size_t)b * NN * 3;
    const int j0 = jb * JCH;
    for (int t = threadIdx.x; t < JCH; t += 256) {
        const int j = j0 + t;
        float a = xb[3 * j], c = xb[3 * j + 1], d = xb[3 * j + 2];
        s4[t] = make_float4(a, c, d, a * a + c * c + d * d);
    }
    __syncthreads();
    const int lc = threadIdx.x & 63;
    const int part = threadIdx.x >> 6;    // wave-uniform
    const int i = blockIdx.x * CPB + lc;
    const float cx = xb[3 * i], cy = xb[3 * i + 1], cz = xb[3 * i + 2];
    const float cw = cx * cx + cy * cy + cz * cz;
    float s0 = INFINITY, s1 = INFINITY, s2 = INFINITY;
    int i0 = -1, i1 = -1, i2 = -1;
    float dsum = 0.f;
    const int tbeg = part * JS;
    for (int t = tbeg; t < tbeg + JS; ++t) {
        float4 p = s4[t];                 // wave-uniform addr -> broadcast
        float sq = fmaxf(cw + p.w - 2.0f * (cx * p.x + cy * p.y + cz * p.z), 0.0f);
        dsum += sqrtf(sq + 1e-12f);
        top3_insert(sq, j0 + t, s0, s1, s2, i0, i1, i2);
    }
    msq[part][lc][0] = s0; msq[part][lc][1] = s1; msq[part][lc][2] = s2;
    mix[part][lc][0] = i0; mix[part][lc][1] = i1; mix[part][lc][2] = i2;
    mds[part][lc] = dsum;
    __syncthreads();
    if (part == 0) {
        float ds = dsum;
        for (int p = 1; p < WPB; ++p) {   // increasing-j order
            ds += mds[p][lc];
            for (int k = 0; k < 3; ++k)
                top3_insert(msq[p][lc][k], mix[p][lc][k], s0, s1, s2, i0, i1, i2);
        }
        const int pi = (b * NJB + jb) * NN + i;
        psq[pi * 3] = s0; psq[pi * 3 + 1] = s1; psq[pi * 3 + 2] = s2;
        pix[pi * 3] = i0; pix[pi * 3 + 1] = i1; pix[pi * 3 + 2] = i2;
        pds[pi] = ds;
    }
}

// Stage B: merge NJB partials per center, exp incidence, de, atomic dv.
__global__ void k_dist_merge(const float* __restrict__ psq, const int* __restrict__ pix,
                             const float* __restrict__ pds,
                             int* __restrict__ idx, float* __restrict__ vals,
                             float* __restrict__ de, float* __restrict__ dv) {
    const int g = blockIdx.x * 256 + threadIdx.x;   // [0, B*NN)
    const int b = g >> 11, i = g & (NN - 1);
    float s0 = INFINITY, s1 = INFINITY, s2 = INFINITY;
    int i0 = -1, i1 = -1, i2 = -1;
    float ds = 0.f;
    for (int jb = 0; jb < NJB; ++jb) {    // increasing-j order
        const int pi = (b * NJB + jb) * NN + i;
        ds += pds[pi];
        for (int k = 0; k < 3; ++k)
            top3_insert(psq[pi * 3 + k], pix[pi * 3 + k], s0, s1, s2, i0, i1, i2);
    }
    const float avg = ds * (1.0f / NN);
    const float inva2 = 1.0f / (avg * avg);
    const float v0 = expf(-s0 * inva2);
    const float v1 = expf(-s1 * inva2);
    const float v2 = expf(-s2 * inva2);
    const int base = g * 3;
    idx[base] = i0; idx[base + 1] = i1; idx[base + 2] = i2;
    vals[base] = v0; vals[base + 1] = v1; vals[base + 2] = v2;
    de[g] = v0 + v1 + v2;
    atomicAdd(&dv[b * NN + i0], v0);
    atomicAdd(&dv[b * NN + i1], v1);
    atomicAdd(&dv[b * NN + i2], v2);
}

// K2: first G-application on W1. One block per edge; gather 3 rows, scatter 3 rows.
__global__ void k_conv1(const float* __restrict__ W1, const int* __restrict__ idx,
                        const float* __restrict__ vals, const float* __restrict__ de,
                        const float* __restrict__ dv, float* __restrict__ Z1) {
    const int e = blockIdx.x, b = blockIdx.y, h = threadIdx.x;
    const int base = (b * NN + e) * 3;
    const int j0 = idx[base], j1 = idx[base + 1], j2 = idx[base + 2];
    const float v0 = vals[base], v1 = vals[base + 1], v2 = vals[base + 2];
    const float ide = 1.0f / de[b * NN + e];
    const float g0 = v0 * rsqrtf(dv[b * NN + j0]);
    const float g1 = v1 * rsqrtf(dv[b * NN + j1]);
    const float g2 = v2 * rsqrtf(dv[b * NN + j2]);
    const float y = ide * (g0 * W1[j0 * HD + h] + g1 * W1[j1 * HD + h] + g2 * W1[j2 * HD + h]);
    atomicAdd(&Z1[((size_t)(b * NN + j0)) * HD + h], v0 * y);
    atomicAdd(&Z1[((size_t)(b * NN + j1)) * HD + h], v1 * y);
    atomicAdd(&Z1[((size_t)(b * NN + j2)) * HD + h], v2 * y);
}

// K3: second G-application on f1 = dv2*Z1 + b1.
__global__ void k_conv2(const float* __restrict__ b1, const int* __restrict__ idx,
                        const float* __restrict__ vals, const float* __restrict__ de,
                        const float* __restrict__ dv, const float* __restrict__ Z1,
                        float* __restrict__ Z2) {
    const int e = blockIdx.x, b = blockIdx.y, h = threadIdx.x;
    const int base = (b * NN + e) * 3;
    const int j0 = idx[base], j1 = idx[base + 1], j2 = idx[base + 2];
    const float v0 = vals[base], v1 = vals[base + 1], v2 = vals[base + 2];
    const float ide = 1.0f / de[b * NN + e];
    const float bh = b1[h];
    const float d0 = rsqrtf(dv[b * NN + j0]);
    const float d1 = rsqrtf(dv[b * NN + j1]);
    const float d2 = rsqrtf(dv[b * NN + j2]);
    const float f0 = d0 * Z1[((size_t)(b * NN + j0)) * HD + h] + bh;
    const float f1 = d1 * Z1[((size_t)(b * NN + j1)) * HD + h] + bh;
    const float f2 = d2 * Z1[((size_t)(b * NN + j2)) * HD + h] + bh;
    const float y = ide * (v0 * d0 * f0 + v1 * d1 * f1 + v2 * d2 * f2);
    atomicAdd(&Z2[((size_t)(b * NN + j0)) * HD + h], v0 * y);
    atomicAdd(&Z2[((size_t)(b * NN + j1)) * HD + h], v1 * y);
    atomicAdd(&Z2[((size_t)(b * NN + j2)) * HD + h], v2 * y);
}

// K4a: partial max over 64-node chunks. grid (B, 32) x 128 threads.
__global__ void k_pool1(const float* __restrict__ dv, const float* __restrict__ Z2,
                        float* __restrict__ pmax) {
    const int b = blockIdx.x, ch = blockIdx.y, h = threadIdx.x;
    const int v0 = ch * PCHUNK;
    float mx = -INFINITY;
    for (int v = v0; v < v0 + PCHUNK; ++v) {
        const float d2 = rsqrtf(dv[b * NN + v]);
        mx = fmaxf(mx, d2 * Z2[((size_t)(b * NN + v)) * HD + h]);
    }
    pmax[(b * NCHUNKS + ch) * HD + h] = mx;
}

// K4b: merge partial maxes + classifier. grid B x 128 threads.
__global__ void k_pool2(const float* __restrict__ Wc, const float* __restrict__ bc,
                        const float* __restrict__ pmax, float* __restrict__ out) {
    __shared__ float smax[HD];
    const int b = blockIdx.x, h = threadIdx.x;
    float mx = -INFINITY;
    for (int c = 0; c < NCHUNKS; ++c)
        mx = fmaxf(mx, pmax[(b * NCHUNKS + c) * HD + h]);
    smax[h] = mx;
    __syncthreads();
    if (h < CNUM) {
        float acc = bc[h];
        for (int q = 0; q < HD; ++q) acc += smax[q] * Wc[q * CNUM + h];
        out[b * CNUM + h] = acc;
    }
}

extern "C" void kernel_launch(void* const* d_in, const int* in_sizes, int n_in,
                              void* d_out, int out_size, void* d_ws, size_t ws_size,
                              hipStream_t stream) {
    const float* x  = (const float*)d_in[0];   // [B,N,3]
    const float* W1 = (const float*)d_in[1];   // [N,H1]
    const float* b1 = (const float*)d_in[2];   // [H1]
    const float* Wc = (const float*)d_in[3];   // [H1,C]
    const float* bc = (const float*)d_in[4];   // [C]
    float* out = (float*)d_out;                // [B,C]

    float* ws = (float*)d_ws;
    float* dv   = ws;                                  // B*N           (memset 1)
    float* Z1   = dv + BB * NN;                        // B*N*HD        (memset 1)
    float* Z2   = Z1 + (size_t)BB * NN * HD;           // B*N*HD        (memset 2, after merge)
    float* vals = Z2 + (size_t)BB * NN * HD;           // B*N*3
    float* de   = vals + BB * NN * 3;                  // B*N
    int*   idx  = (int*)(de + BB * NN);                // B*N*3
    float* pmax = (float*)(idx + BB * NN * 3);         // B*32*HD
    // distance partials aliased into Z2 (used only before memset 2):
    float* psq = Z2;                                   // B*NJB*N*3
    int*   pix = (int*)(psq + (size_t)BB * NJB * NN * 3);
    float* pds = (float*)(pix + (size_t)BB * NJB * NN * 3);

    hipMemsetAsync(dv, 0, (size_t)(BB * NN) * (1 + HD) * sizeof(float), stream);
    k_dist_part<<<dim3(NN / CPB, NJB, BB), 256, 0, stream>>>(x, psq, pix, pds);
    k_dist_merge<<<BB * NN / 256, 256, 0, stream>>>(psq, pix, pds, idx, vals, de, dv);
    hipMemsetAsync(Z2, 0, (size_t)BB * NN * HD * sizeof(float), stream);
    k_conv1<<<dim3(NN, BB), HD, 0, stream>>>(W1, idx, vals, de, dv, Z1);
    k_conv2<<<dim3(NN, BB), HD, 0, stream>>>(b1, idx, vals, de, dv, Z1, Z2);
    k_pool1<<<dim3(BB, NCHUNKS), HD, 0, stream>>>(dv, Z2, pmax);
    k_pool2<<<BB, HD, 0, stream>>>(Wc, bc, pmax, out);
}